// Round 5
// baseline (311.157 us; speedup 1.0000x reference)
//
#include <hip/hip_runtime.h>
#include <hip/hip_bf16.h>
#include <stdint.h>

#define B_ 4
#define N_ 2048
#define D_ 1024
#define K_ 16
#define MROWS (B_*N_)      // 8192
#define NC_ 32
#define CLEN_ (N_/NC_)     // 64

typedef unsigned short u16;
typedef __attribute__((ext_vector_type(8))) short bf16x8;
typedef __attribute__((ext_vector_type(4))) float f32x4;

__device__ __forceinline__ u16 f2bf(float f) {
  uint32_t u = __float_as_uint(f);
  u = u + 0x7fffu + ((u >> 16) & 1u);
  return (u16)(u >> 16);
}

// ---------------- cast fp32 -> bf16 (vectorized) ----------------
__global__ __launch_bounds__(256) void cast_kernel(const float* __restrict__ in,
                                                   u16* __restrict__ out, int n) {
  int i = (blockIdx.x * 256 + threadIdx.x) * 4;
  if (i >= n) return;
  float4 v = *(const float4*)(in + i);
  ushort4 o;
  o.x = f2bf(v.x); o.y = f2bf(v.y); o.z = f2bf(v.z); o.w = f2bf(v.w);
  *(ushort4*)(out + i) = o;
}

// ---------------- unit-pipelined bf16 GEMM ----------------
// C[m,n] = sum_k A[m,k] * W[n,k].  M=8192, K=1024.
// BM=128, BN=128, 256 threads = 4 waves (2M x 2N), wave tile 64x64.
// Unit = one BK=32 K-slice of A+B = 16KB LDS.  4-slot ring = 64KB
// -> 2 blocks/CU co-resident (m114 overlap) + counted-vmcnt pipeline:
// per unit u: vmcnt(8) [proves u landed, keeps u+1,u+2 in flight] ->
// barrier -> stage(u+3) -> ds_read(u) -> lgkm(2)/lgkm(0) -> MFMA.
// Race proof: slot(u+3)=slot(u-1); unit u-1 reads are lgkm(0)-complete
// before ANY wave passes barrier u, and stage(u+3) issues after it.
// Swizzle (64B rows, 4x16B chunks): chunk ^= (row&3)^((row>>2)&3),
// involutive on both stage-source and read side (rule 21).
#define GL_LDS(gp, lp) \
  __builtin_amdgcn_global_load_lds( \
      (const __attribute__((address_space(1))) void*)(gp), \
      (__attribute__((address_space(3))) void*)(lp), 16, 0, 0)

#define WAITVM(n)  asm volatile("s_waitcnt vmcnt(" #n ")" ::: "memory")
#define WAITLG(n)  asm volatile("s_waitcnt lgkmcnt(" #n ")" ::: "memory")
#define SCHEDB()   __builtin_amdgcn_sched_barrier(0)

template<bool FUSED>
__global__ __launch_bounds__(256, 2) void gemm_unit(const u16* __restrict__ A,
                                                    const u16* __restrict__ W0,
                                                    const u16* __restrict__ W1,
                                                    float* __restrict__ C0,
                                                    float* __restrict__ C1) {
  __shared__ __align__(16) char lds[4 * 16384];   // 64 KB

  const int tid = threadIdx.x;
  const int w = tid >> 6, l = tid & 63;
  const int wr = w >> 1, wc = w & 1;

  // bijective XCD swizzle (nwg % 8 == 0)
  const int nwg = FUSED ? 1024 : 512;
  const int NBN = FUSED ? 16 : 8;
  const int orig = blockIdx.x;
  const int wg = (orig & 7) * (nwg >> 3) + (orig >> 3);
  const int bm = wg / NBN;
  const int bn = wg % NBN;

  const u16* W;
  float* C;
  bool fgate = false;
  int ncol0;
  if (FUSED && bn >= 8) {
    W = W1; C = C1; fgate = true; ncol0 = (bn - 8) * 128;
  } else {
    W = W0; C = C0; ncol0 = bn * 128;
  }

  // ---- staging sources (pre-swizzled 16B chunk within 64B row) ----
  // lane l fills LDS row (l>>2), chunk (l&3); source chunk = (l&3)^f(row),
  // f(row) = (row&3)^((row>>2)&3) = ((l>>2)&3)^((l>>4)&3)
  const int pw = (((l & 3) ^ ((l >> 2) & 3) ^ ((l >> 4) & 3))) * 8;  // elems
  const u16* aS0 = A + (size_t)(bm * 128 + (w * 2 + 0) * 16 + (l >> 2)) * 1024 + pw;
  const u16* aS1 = A + (size_t)(bm * 128 + (w * 2 + 1) * 16 + (l >> 2)) * 1024 + pw;
  const u16* bS0 = W + (size_t)(ncol0 + (w * 2 + 0) * 16 + (l >> 2)) * 1024 + pw;
  const u16* bS1 = W + (size_t)(ncol0 + (w * 2 + 1) * 16 + (l >> 2)) * 1024 + pw;
  const int lA0 = (w * 2 + 0) * 1024;   // LDS byte offsets (wave-uniform)
  const int lA1 = (w * 2 + 1) * 1024;

#define STAGE_U(u) do { \
    const int _s = ((u) & 3) * 16384; \
    GL_LDS(aS0 + (u) * 32, lds + _s + lA0); \
    GL_LDS(aS1 + (u) * 32, lds + _s + lA1); \
    GL_LDS(bS0 + (u) * 32, lds + _s + 8192 + lA0); \
    GL_LDS(bS1 + (u) * 32, lds + _s + 8192 + lA1); \
  } while (0)

  // ---- fragment read addressing ----
  // lane wants global chunk (l>>4) of row X*16+(l&15):
  // LDS chunk = (l>>4)^(l&3)^((l>>2)&3)
  const int pr = ((l >> 4) ^ (l & 3) ^ ((l >> 2) & 3)) * 16;       // bytes
  const int aro = (wr * 64 + (l & 15)) * 64 + pr;                  // + mi*1024
  const int bro = 8192 + (wc * 64 + (l & 15)) * 64 + pr;           // + ni*1024

  f32x4 acc[4][4] = {};

#define COMPUTE_U(u) do { \
    const char* S = lds + ((u) & 3) * 16384; \
    bf16x8 a0 = *(const bf16x8*)(S + aro); \
    bf16x8 a1 = *(const bf16x8*)(S + aro + 1024); \
    bf16x8 b0 = *(const bf16x8*)(S + bro); \
    bf16x8 b1 = *(const bf16x8*)(S + bro + 1024); \
    bf16x8 b2 = *(const bf16x8*)(S + bro + 2048); \
    bf16x8 b3 = *(const bf16x8*)(S + bro + 3072); \
    SCHEDB(); \
    bf16x8 a2 = *(const bf16x8*)(S + aro + 2048); \
    bf16x8 a3 = *(const bf16x8*)(S + aro + 3072); \
    WAITLG(2); SCHEDB(); \
    __builtin_amdgcn_s_setprio(1); \
    acc[0][0] = __builtin_amdgcn_mfma_f32_16x16x32_bf16(a0, b0, acc[0][0], 0, 0, 0); \
    acc[0][1] = __builtin_amdgcn_mfma_f32_16x16x32_bf16(a0, b1, acc[0][1], 0, 0, 0); \
    acc[0][2] = __builtin_amdgcn_mfma_f32_16x16x32_bf16(a0, b2, acc[0][2], 0, 0, 0); \
    acc[0][3] = __builtin_amdgcn_mfma_f32_16x16x32_bf16(a0, b3, acc[0][3], 0, 0, 0); \
    acc[1][0] = __builtin_amdgcn_mfma_f32_16x16x32_bf16(a1, b0, acc[1][0], 0, 0, 0); \
    acc[1][1] = __builtin_amdgcn_mfma_f32_16x16x32_bf16(a1, b1, acc[1][1], 0, 0, 0); \
    acc[1][2] = __builtin_amdgcn_mfma_f32_16x16x32_bf16(a1, b2, acc[1][2], 0, 0, 0); \
    acc[1][3] = __builtin_amdgcn_mfma_f32_16x16x32_bf16(a1, b3, acc[1][3], 0, 0, 0); \
    __builtin_amdgcn_s_setprio(0); \
    WAITLG(0); SCHEDB(); \
    __builtin_amdgcn_s_setprio(1); \
    acc[2][0] = __builtin_amdgcn_mfma_f32_16x16x32_bf16(a2, b0, acc[2][0], 0, 0, 0); \
    acc[2][1] = __builtin_amdgcn_mfma_f32_16x16x32_bf16(a2, b1, acc[2][1], 0, 0, 0); \
    acc[2][2] = __builtin_amdgcn_mfma_f32_16x16x32_bf16(a2, b2, acc[2][2], 0, 0, 0); \
    acc[2][3] = __builtin_amdgcn_mfma_f32_16x16x32_bf16(a2, b3, acc[2][3], 0, 0, 0); \
    acc[3][0] = __builtin_amdgcn_mfma_f32_16x16x32_bf16(a3, b0, acc[3][0], 0, 0, 0); \
    acc[3][1] = __builtin_amdgcn_mfma_f32_16x16x32_bf16(a3, b1, acc[3][1], 0, 0, 0); \
    acc[3][2] = __builtin_amdgcn_mfma_f32_16x16x32_bf16(a3, b2, acc[3][2], 0, 0, 0); \
    acc[3][3] = __builtin_amdgcn_mfma_f32_16x16x32_bf16(a3, b3, acc[3][3], 0, 0, 0); \
    __builtin_amdgcn_s_setprio(0); \
  } while (0)

  // prologue: stage units 0,1,2 (12 loads in flight)
  STAGE_U(0);
  STAGE_U(1);
  STAGE_U(2);

#pragma unroll
  for (int u = 0; u < 32; ++u) {
    if (u <= 29)      WAITVM(8);    // units u+1,u+2 may pend; u proven landed
    else if (u == 30) WAITVM(4);
    else              WAITVM(0);
    __builtin_amdgcn_s_barrier();
    SCHEDB();
    if (u + 3 < 32) STAGE_U(u + 3); // into slot(u-1): readers done pre-barrier
    COMPUTE_U(u);
  }

  // epilogue
  const int orow0 = bm * 128 + wr * 64 + (l >> 4) * 4;
  const int ocol0 = ncol0 + wc * 64 + (l & 15);
#pragma unroll
  for (int m = 0; m < 4; ++m) {
#pragma unroll
    for (int n = 0; n < 4; ++n) {
#pragma unroll
      for (int r = 0; r < 4; ++r) {
        int row = orow0 + m * 16 + r;
        int col = ocol0 + n * 16;
        float v = acc[m][n][r];
        if (FUSED && fgate) {
          float ls = (v >= 0.0f) ? -log1pf(expf(-v)) : (v - log1pf(expf(v)));
          v = expf(ls * (1.0f / 16.0f));
        }
        C[(size_t)row * 1024 + col] = v;
      }
    }
  }
#undef STAGE_U
#undef COMPUTE_U
}

// ---------------- e/s projections ----------------
__global__ __launch_bounds__(256) void es_proj(const float* __restrict__ x,
                                               const float* __restrict__ We,
                                               const float* __restrict__ Ws,
                                               float* __restrict__ e,
                                               float* __restrict__ s) {
  int row = blockIdx.x * 4 + (threadIdx.x >> 6);
  int l = threadIdx.x & 63;
  const float* xr = x + (size_t)row * D_;
  float4 xv[4];
#pragma unroll
  for (int j = 0; j < 4; ++j) xv[j] = *(const float4*)(xr + j * 256 + l * 4);
  float pe[K_], ps[K_];
#pragma unroll
  for (int k = 0; k < K_; ++k) {
    float ae = 0.f, as_ = 0.f;
#pragma unroll
    for (int j = 0; j < 4; ++j) {
      float4 wv = *(const float4*)(We + (size_t)k * D_ + j * 256 + l * 4);
      float4 sv = *(const float4*)(Ws + (size_t)k * D_ + j * 256 + l * 4);
      ae  += xv[j].x * wv.x + xv[j].y * wv.y + xv[j].z * wv.z + xv[j].w * wv.w;
      as_ += xv[j].x * sv.x + xv[j].y * sv.y + xv[j].z * sv.z + xv[j].w * sv.w;
    }
    pe[k] = ae; ps[k] = as_;
  }
#pragma unroll
  for (int k = 0; k < K_; ++k) {
    float ae = pe[k], as_ = ps[k];
    for (int off = 32; off > 0; off >>= 1) {
      ae  += __shfl_down(ae, off);
      as_ += __shfl_down(as_, off);
    }
    if (l == 0) {
      e[(size_t)row * K_ + k] = ae;
      s[(size_t)row * K_ + k] = as_;
    }
  }
}

// ---------------- scan pass1 ----------------
__global__ __launch_bounds__(256) void scan_pass1(const float* __restrict__ ibuf,
                                                  const float* __restrict__ fbuf,
                                                  const float* __restrict__ ebuf,
                                                  float* __restrict__ Asc,
                                                  float* __restrict__ Psc) {
  int bid = blockIdx.x;
  int dq = bid & 3, c = (bid >> 2) & (NC_ - 1), b = bid >> 7;
  int d = dq * 256 + threadIdx.x;
  int t0 = c * CLEN_;
  float m[K_];
#pragma unroll
  for (int k = 0; k < K_; ++k) m[k] = 0.f;
  float p = 1.0f;
  const float* ip = ibuf + ((size_t)b * N_ + t0) * D_ + d;
  const float* fp = fbuf + ((size_t)b * N_ + t0) * D_ + d;
  const float* ep = ebuf + ((size_t)b * N_ + t0) * K_;
  for (int t = 0; t < CLEN_; ++t) {
    float it = ip[(size_t)t * D_];
    float ft = fp[(size_t)t * D_];
    p *= ft;
#pragma unroll
    for (int k = 0; k < K_; ++k) m[k] = ft * m[k] + ep[t * K_ + k] * it;
  }
  float* ap = Asc + (((size_t)b * NC_ + c) * K_) * D_ + d;
#pragma unroll
  for (int k = 0; k < K_; ++k) ap[(size_t)k * D_] = m[k];
  Psc[((size_t)b * NC_ + c) * D_ + d] = p;
}

// ---------------- scan pass2 ----------------
__global__ __launch_bounds__(256) void scan_pass2(const float* __restrict__ Asc,
                                                  const float* __restrict__ Psc,
                                                  float* __restrict__ Ssc) {
  int idx = blockIdx.x * 256 + threadIdx.x;
  int d = idx & (D_ - 1);
  int k = (idx >> 10) & (K_ - 1);
  int b = idx >> 14;
  float M = 0.f;
  for (int c = 0; c < NC_; ++c) {
    size_t base = (((size_t)b * NC_ + c) * K_ + k) * D_ + d;
    float a = Asc[base];
    float pp = Psc[((size_t)b * NC_ + c) * D_ + d];
    Ssc[base] = M;
    M = pp * M + a;
  }
}

// ---------------- scan pass3 ----------------
__global__ __launch_bounds__(256) void scan_pass3(float* __restrict__ ibuf,
                                                  const float* __restrict__ fbuf,
                                                  const float* __restrict__ ebuf,
                                                  const float* __restrict__ sbuf,
                                                  const float* __restrict__ Ssc) {
  int bid = blockIdx.x;
  int dq = bid & 3, c = (bid >> 2) & (NC_ - 1), b = bid >> 7;
  int d = dq * 256 + threadIdx.x;
  int t0 = c * CLEN_;
  float m[K_];
  const float* sp0 = Ssc + (((size_t)b * NC_ + c) * K_) * D_ + d;
#pragma unroll
  for (int k = 0; k < K_; ++k) m[k] = sp0[(size_t)k * D_];
  float* ip = ibuf + ((size_t)b * N_ + t0) * D_ + d;
  const float* fp = fbuf + ((size_t)b * N_ + t0) * D_ + d;
  const float* ep = ebuf + ((size_t)b * N_ + t0) * K_;
  const float* zp = sbuf + ((size_t)b * N_ + t0) * K_;
  for (int t = 0; t < CLEN_; ++t) {
    float it = ip[(size_t)t * D_];
    float ft = fp[(size_t)t * D_];
    float y = 0.f;
#pragma unroll
    for (int k = 0; k < K_; ++k) {
      m[k] = ft * m[k] + ep[t * K_ + k] * it;
      y += zp[t * K_ + k] * m[k];
    }
    ip[(size_t)t * D_] = y;
  }
}

// ---------------- LayerNorm -> bf16 ----------------
__global__ __launch_bounds__(256) void ln_kernel(const float* __restrict__ y,
                                                 const float* __restrict__ gamma,
                                                 const float* __restrict__ beta,
                                                 u16* __restrict__ yn) {
  int row = blockIdx.x * 4 + (threadIdx.x >> 6);
  int l = threadIdx.x & 63;
  const float* yr = y + (size_t)row * D_;
  float4 v[4];
  float sum = 0.f;
#pragma unroll
  for (int j = 0; j < 4; ++j) {
    v[j] = *(const float4*)(yr + j * 256 + l * 4);
    sum += v[j].x + v[j].y + v[j].z + v[j].w;
  }
  for (int off = 32; off > 0; off >>= 1) sum += __shfl_xor(sum, off);
  float mu = sum * (1.0f / D_);
  float vs = 0.f;
#pragma unroll
  for (int j = 0; j < 4; ++j) {
    float dx = v[j].x - mu; vs += dx * dx;
    dx = v[j].y - mu; vs += dx * dx;
    dx = v[j].z - mu; vs += dx * dx;
    dx = v[j].w - mu; vs += dx * dx;
  }
  for (int off = 32; off > 0; off >>= 1) vs += __shfl_xor(vs, off);
  float rstd = rsqrtf(vs * (1.0f / D_) + 1e-5f);
#pragma unroll
  for (int j = 0; j < 4; ++j) {
    int col = j * 256 + l * 4;
    float4 g = *(const float4*)(gamma + col);
    float4 bt = *(const float4*)(beta + col);
    ushort4 o;
    o.x = f2bf((v[j].x - mu) * rstd * g.x + bt.x);
    o.y = f2bf((v[j].y - mu) * rstd * g.y + bt.y);
    o.z = f2bf((v[j].z - mu) * rstd * g.z + bt.z);
    o.w = f2bf((v[j].w - mu) * rstd * g.w + bt.w);
    *(ushort4*)(yn + (size_t)row * D_ + col) = o;
  }
}

extern "C" void kernel_launch(void* const* d_in, const int* in_sizes, int n_in,
                              void* d_out, int out_size, void* d_ws, size_t ws_size,
                              hipStream_t stream) {
  const float* x     = (const float*)d_in[0];
  const float* Wi    = (const float*)d_in[1];
  const float* We    = (const float*)d_in[2];
  const float* Wf    = (const float*)d_in[3];
  const float* Ws    = (const float*)d_in[4];
  const float* gamma = (const float*)d_in[5];
  const float* beta  = (const float*)d_in[6];
  const float* Wo    = (const float*)d_in[7];
  float* out = (float*)d_out;

  char* p = (char*)d_ws;
  u16* xb  = (u16*)p;  p += (size_t)MROWS * D_ * 2;
  u16* wib = (u16*)p;  p += (size_t)D_ * D_ * 2;
  u16* wfb = (u16*)p;  p += (size_t)D_ * D_ * 2;
  u16* wob = (u16*)p;  p += (size_t)D_ * D_ * 2;
  float* ibuf = (float*)p; p += (size_t)MROWS * D_ * 4;
  float* fbuf = (float*)p; p += (size_t)MROWS * D_ * 4;
  float* ebuf = (float*)p; p += (size_t)MROWS * K_ * 4;
  float* sbuf = (float*)p; p += (size_t)MROWS * K_ * 4;
  float* Asc  = (float*)p; p += (size_t)B_ * NC_ * K_ * D_ * 4;
  float* Ssc  = (float*)p; p += (size_t)B_ * NC_ * K_ * D_ * 4;
  float* Psc  = (float*)p; p += (size_t)B_ * NC_ * D_ * 4;

  cast_kernel<<<MROWS * D_ / 1024, 256, 0, stream>>>(x, xb, MROWS * D_);
  cast_kernel<<<D_ * D_ / 1024, 256, 0, stream>>>(Wi, wib, D_ * D_);
  cast_kernel<<<D_ * D_ / 1024, 256, 0, stream>>>(Wf, wfb, D_ * D_);
  cast_kernel<<<D_ * D_ / 1024, 256, 0, stream>>>(Wo, wob, D_ * D_);

  // fused i+f projection: 1024 blocks x 256 threads, 2 blocks/CU
  gemm_unit<true><<<1024, 256, 0, stream>>>(xb, wib, wfb, ibuf, fbuf);

  es_proj<<<MROWS / 4, 256, 0, stream>>>(x, We, Ws, ebuf, sbuf);

  scan_pass1<<<B_ * NC_ * 4, 256, 0, stream>>>(ibuf, fbuf, ebuf, Asc, Psc);
  scan_pass2<<<B_ * K_ * D_ / 256, 256, 0, stream>>>(Asc, Psc, Ssc);
  scan_pass3<<<B_ * NC_ * 4, 256, 0, stream>>>(ibuf, fbuf, ebuf, sbuf, Ssc);

  u16* ynb = xb;
  ln_kernel<<<MROWS / 4, 256, 0, stream>>>(ibuf, gamma, beta, ynb);

  // o-proj: 512 blocks, 2 blocks/CU
  gemm_unit<false><<<512, 256, 0, stream>>>(ynb, wob, nullptr, out, nullptr);
}